// Round 15
// baseline (17.359 us; speedup 1.0000x reference)
//
#include <hip/hip_runtime.h>

#define B_DIM 32
#define O_DIM 1000
#define M_DIM 100
#define F_DIM 32
#define DS 6
#define DD 3
#define SEG 16      // 512 blocks = exactly 2/CU (R14 optimum)
#define CHUNK 63    // 16*63=1008, last seg guarded (n=55)
#define OSUB 9      // o-subgroups per block
#define TRIPS 7     // ceil(CHUNK/OSUB)
#define MT 25       // m-tile per gat_final block
#define PART_FLOATS ((size_t)B_DIM * SEG * M_DIM * 8)   // 1.64 MB

// Kernel 1: per (batch, o-segment) block computes partial softmax sums per
// m-column. partial: [B][SEG][M][8] (0=denom, 1=sum p*pt, 2..7=sum p*ro[,d])
__global__ __launch_bounds__(256) void gat_partial(
    const float* __restrict__ raw_opes,   // [B,O,DS]
    const float* __restrict__ raw_mas,    // [B,M,DD]
    const float* __restrict__ proc_time,  // [B,O,M]
    const int*   __restrict__ adj,        // [Btot,O,M]
    const int*   __restrict__ bidx,       // [B]
    const float* __restrict__ Wsrc,       // [DS,F]
    const float* __restrict__ Wdst,       // [DD,F]
    const float* __restrict__ Wedge,      // [F]
    const float* __restrict__ attn_l,     // [F]
    const float* __restrict__ attn_r,     // [F]
    float* __restrict__ partial)
{
    const int b   = blockIdx.x / SEG;
    const int seg = blockIdx.x % SEG;
    const int t   = threadIdx.x;
    const int o0  = seg * CHUNK;
    const int n   = min(CHUNK, O_DIM - o0);   // 63, except last seg = 55

    __shared__ __align__(16) float ro_s[CHUNK * DS];          // 1.5 KB
    __shared__ __align__(16) float part_s[OSUB][M_DIM][12];   // 43.2 KB, 16B-aligned rows
    __shared__ __align__(16) float rm_s[M_DIM * DD];          // 4.8 KB staged raw_mas[b]
    __shared__ float wfold[10];                               // wl[0..5], we, wr[0..2]

    const int mg = t % 25;   // consecutive lanes -> consecutive m (coalesced)
    const int g  = t / 25;   // o-subgroup 0..8 (t<225)

    // Issue the hot-loop loads FIRST: 14 outstanding 16B loads/thread.
    float4 pt[TRIPS];
    int4   av[TRIPS];
    if (t < 25 * OSUB) {
        const float* ptp = proc_time + ((size_t)b * O_DIM + o0) * M_DIM + mg * 4;
        #pragma unroll
        for (int k = 0; k < TRIPS; ++k) {
            const int rc = min(g + k * OSUB, n - 1);
            pt[k] = *(const float4*)(ptp + rc * M_DIM);
        }
        const int* adp = adj + ((size_t)bidx[b] * O_DIM + o0) * M_DIM + mg * 4;
        #pragma unroll
        for (int k = 0; k < TRIPS; ++k) {
            const int rc = min(g + k * OSUB, n - 1);
            av[k] = *(const int4*)(adp + rc * M_DIM);
        }
    }

    // Stage this segment's raw_opes (n*6 <= 378 floats).
    {
        const float* rop = raw_opes + ((size_t)b * O_DIM + o0) * DS;
        const int tot = n * DS;
        if (t < tot) ro_s[t] = rop[t];
        if (t + 256 < tot) ro_s[t + 256] = rop[t + 256];
    }
    // Stage raw_mas[b] (300 floats) — latency hides under the prefetch burst.
    {
        const float* rmp = raw_mas + (size_t)b * M_DIM * DD;
        for (int i = t; i < M_DIM * DD; i += 256) rm_s[i] = rmp[i];
    }

    // Wave-parallel weight fold on lanes 224-255 (only lane 224 has other
    // duties) — keeps the fold off the prefetch lanes' critical path.
    if (t >= 224) {
        const int f = t & 31;
        float al = attn_l[f], ar = attn_r[f];
        float p[10];
        #pragma unroll
        for (int d = 0; d < DS; ++d) p[d] = Wsrc[d * F_DIM + f] * al;
        p[6] = Wedge[f] * al;
        #pragma unroll
        for (int d = 0; d < DD; ++d) p[7 + d] = Wdst[d * F_DIM + f] * ar;
        #pragma unroll
        for (int s = 1; s < 32; s <<= 1) {
            #pragma unroll
            for (int k = 0; k < 10; ++k) p[k] += __shfl_xor(p[k], s);
        }
        if (f == 0) {
            #pragma unroll
            for (int k = 0; k < 10; ++k) wfold[k] = p[k];
        }
    }
    __syncthreads();

    if (t < 25 * OSUB) {
        float wl[DS], wr[DD], we;
        #pragma unroll
        for (int d = 0; d < DS; ++d) wl[d] = wfold[d];
        we = wfold[6];
        #pragma unroll
        for (int d = 0; d < DD; ++d) wr[d] = wfold[7 + d];

        const float* rm = rm_s + mg * 4 * DD;   // 12 consecutive floats, LDS
        float4 er;
        er.x = fmaf(rm[0], wr[0], fmaf(rm[1],  wr[1], rm[2]  * wr[2]));
        er.y = fmaf(rm[3], wr[0], fmaf(rm[4],  wr[1], rm[5]  * wr[2]));
        er.z = fmaf(rm[6], wr[0], fmaf(rm[7],  wr[1], rm[8]  * wr[2]));
        er.w = fmaf(rm[9], wr[0], fmaf(rm[10], wr[1], rm[11] * wr[2]));

        float4 den = make_float4(0, 0, 0, 0), spa = make_float4(0, 0, 0, 0);
        float4 sd[DS];
        #pragma unroll
        for (int d = 0; d < DS; ++d) sd[d] = make_float4(0, 0, 0, 0);

        #pragma unroll
        for (int k = 0; k < TRIPS; ++k) {
            const int row = g + k * OSUB;
            const int rc  = min(row, n - 1);
            const bool valid = row < n;
            float ro[DS];
            #pragma unroll
            for (int d = 0; d < DS; ++d) ro[d] = ro_s[rc * DS + d];
            float elr = 0.f;
            #pragma unroll
            for (int d = 0; d < DS; ++d) elr = fmaf(ro[d], wl[d], elr);

            float s0 = elr + er.x + we * pt[k].x;
            float s1 = elr + er.y + we * pt[k].y;
            float s2 = elr + er.z + we * pt[k].z;
            float s3 = elr + er.w + we * pt[k].w;
            s0 = fmaxf(s0, 0.2f * s0); s1 = fmaxf(s1, 0.2f * s1);
            s2 = fmaxf(s2, 0.2f * s2); s3 = fmaxf(s3, 0.2f * s3);
            float p0 = (valid && av[k].x == 1) ? __expf(s0) : 0.f;
            float p1 = (valid && av[k].y == 1) ? __expf(s1) : 0.f;
            float p2 = (valid && av[k].z == 1) ? __expf(s2) : 0.f;
            float p3 = (valid && av[k].w == 1) ? __expf(s3) : 0.f;
            den.x += p0; den.y += p1; den.z += p2; den.w += p3;
            spa.x = fmaf(p0, pt[k].x, spa.x); spa.y = fmaf(p1, pt[k].y, spa.y);
            spa.z = fmaf(p2, pt[k].z, spa.z); spa.w = fmaf(p3, pt[k].w, spa.w);
            #pragma unroll
            for (int d = 0; d < DS; ++d) {
                sd[d].x = fmaf(p0, ro[d], sd[d].x);
                sd[d].y = fmaf(p1, ro[d], sd[d].y);
                sd[d].z = fmaf(p2, ro[d], sd[d].z);
                sd[d].w = fmaf(p3, ro[d], sd[d].w);
            }
        }

        #pragma unroll
        for (int j = 0; j < 4; ++j) {
            const int m = mg * 4 + j;
            float* ps = part_s[g][m];
            ps[0] = j == 0 ? den.x : j == 1 ? den.y : j == 2 ? den.z : den.w;
            ps[1] = j == 0 ? spa.x : j == 1 ? spa.y : j == 2 ? spa.z : spa.w;
            #pragma unroll
            for (int d = 0; d < DS; ++d)
                ps[2 + d] = j == 0 ? sd[d].x : j == 1 ? sd[d].y : j == 2 ? sd[d].z : sd[d].w;
        }
    }
    __syncthreads();

    // Reduce over OSUB groups (ds_read_b128 thanks to 12-stride) and write.
    if (t < 2 * M_DIM) {
        const int m = t % M_DIM, half = t / M_DIM;
        float4 a = make_float4(0, 0, 0, 0);
        #pragma unroll
        for (int gg = 0; gg < OSUB; ++gg) {
            const float4 x = *(const float4*)&part_s[gg][m][half * 4];
            a.x += x.x; a.y += x.y; a.z += x.z; a.w += x.w;
        }
        *(float4*)(partial + (((size_t)b * SEG + seg) * M_DIM + m) * 8 + half * 4) = a;
    }
}

// Kernel 2: reduce segments, normalize, emit sigmoid output. Grid = B*4.
__global__ __launch_bounds__(256) void gat_final(
    const float* __restrict__ raw_mas,    // [B,M,DD]
    const float* __restrict__ Wsrc,       // [DS,F]
    const float* __restrict__ Wdst,       // [DD,F]
    const float* __restrict__ Wedge,      // [F]
    const float* __restrict__ attn_r,     // [F]
    const float* __restrict__ partial,
    float* __restrict__ out)              // [B,M,F]
{
    const int b  = blockIdx.x >> 2;
    const int m0 = (blockIdx.x & 3) * MT;
    const int t  = threadIdx.x;

    __shared__ float smd[MT][9];
    __shared__ float wr_s[DD];

    // Wave-parallel attn_r fold (wave 3, overlaps the reduce phase).
    if (t >= 192) {
        const int f = t & 31;
        float ar = attn_r[f];
        float p[DD];
        #pragma unroll
        for (int d = 0; d < DD; ++d) p[d] = Wdst[d * F_DIM + f] * ar;
        #pragma unroll
        for (int s = 1; s < 32; s <<= 1) {
            #pragma unroll
            for (int d = 0; d < DD; ++d) p[d] += __shfl_xor(p[d], s);
        }
        if ((t & 63) == 0) {
            #pragma unroll
            for (int d = 0; d < DD; ++d) wr_s[d] = p[d];
        }
    }

    if (t < MT * 8) {
        const int ml = t % MT;
        const int k  = t / MT;
        const float* p = partial + (((size_t)b * SEG) * M_DIM + m0 + ml) * 8 + k;
        float acc = 0.f;
        #pragma unroll
        for (int s = 0; s < SEG; ++s) acc += p[(size_t)s * M_DIM * 8];
        smd[ml][k] = acc;
    }
    __syncthreads();

    if (t < MT) {
        const float* rm = raw_mas + ((size_t)b * M_DIM + m0 + t) * DD;
        float er = fmaf(rm[0], wr_s[0], fmaf(rm[1], wr_s[1], rm[2] * wr_s[2]));
        float skk = 2.f * er;
        skk = fmaxf(skk, 0.2f * skk);
        float pkk = __expf(skk);
        float den = smd[t][0], spa = smd[t][1];
        float s0 = smd[t][2], s1 = smd[t][3], s2 = smd[t][4],
              s3 = smd[t][5], s4 = smd[t][6], s5 = smd[t][7];
        float inv = 1.f / (den + pkk);
        smd[t][0] = s0 * inv; smd[t][1] = s1 * inv; smd[t][2] = s2 * inv;
        smd[t][3] = s3 * inv; smd[t][4] = s4 * inv; smd[t][5] = s5 * inv;
        smd[t][6] = spa * inv;
        smd[t][7] = pkk * inv;
    }
    __syncthreads();

    for (int idx = t; idx < MT * F_DIM; idx += 256) {
        const int ml = idx >> 5;
        const int f  = idx & 31;
        float v = smd[ml][6] * Wedge[f];
        #pragma unroll
        for (int d = 0; d < DS; ++d) v = fmaf(smd[ml][d], Wsrc[d * F_DIM + f], v);
        const float* rm = raw_mas + ((size_t)b * M_DIM + m0 + ml) * DD;
        float fd = 0.f;
        #pragma unroll
        for (int d = 0; d < DD; ++d) fd = fmaf(rm[d], Wdst[d * F_DIM + f], fd);
        v = fmaf(fd, smd[ml][7], v);
        out[((size_t)b * M_DIM + m0 + ml) * F_DIM + f] = 1.f / (1.f + __expf(-v));
    }
}

extern "C" void kernel_launch(void* const* d_in, const int* in_sizes, int n_in,
                              void* d_out, int out_size, void* d_ws, size_t ws_size,
                              hipStream_t stream) {
    const float* raw_opes  = (const float*)d_in[0];
    const float* raw_mas   = (const float*)d_in[1];
    const float* proc_time = (const float*)d_in[2];
    const int*   adj       = (const int*)d_in[3];
    const int*   bidx      = (const int*)d_in[4];
    const float* Wsrc      = (const float*)d_in[5];
    const float* Wdst      = (const float*)d_in[6];
    const float* Wedge     = (const float*)d_in[7];
    const float* attn_l    = (const float*)d_in[8];
    const float* attn_r    = (const float*)d_in[9];
    float* out     = (float*)d_out;
    float* partial = (float*)d_ws;   // [B,SEG,M,8] = 1.64 MB

    gat_partial<<<B_DIM * SEG, 256, 0, stream>>>(raw_opes, raw_mas, proc_time, adj, bidx,
                                                 Wsrc, Wdst, Wedge, attn_l, attn_r, partial);
    gat_final<<<B_DIM * 4, 256, 0, stream>>>(raw_mas, Wsrc, Wdst, Wedge, attn_r, partial, out);
}

// Round 16
// 15.625 us; speedup vs baseline: 1.1110x; 1.1110x over previous
//
#include <hip/hip_runtime.h>

#define B_DIM 32
#define O_DIM 1000
#define M_DIM 100
#define F_DIM 32
#define DS 6
#define DD 3
#define SEG 16      // o-segments per batch -> 512 blocks = exactly 2/CU
#define CHUNK 63    // ceil-ish: 16*63=1008, last seg guarded (n=55)
#define OSUB 9      // o-subgroups per block
#define TRIPS 7     // CHUNK / OSUB
#define MT 25       // m-tile per gat_final block
#define PART_FLOATS ((size_t)B_DIM * SEG * M_DIM * 8)   // 1.64 MB

// Kernel 1: per (batch, o-segment) block computes partial softmax sums per
// m-column. partial: [B][SEG][M][8] (0=denom, 1=sum p*pt, 2..7=sum p*ro[,d])
__global__ __launch_bounds__(256) void gat_partial(
    const float* __restrict__ raw_opes,   // [B,O,DS]
    const float* __restrict__ raw_mas,    // [B,M,DD]
    const float* __restrict__ proc_time,  // [B,O,M]
    const int*   __restrict__ adj,        // [Btot,O,M]
    const int*   __restrict__ bidx,       // [B]
    const float* __restrict__ Wsrc,       // [DS,F]
    const float* __restrict__ Wdst,       // [DD,F]
    const float* __restrict__ Wedge,      // [F]
    const float* __restrict__ attn_l,     // [F]
    const float* __restrict__ attn_r,     // [F]
    float* __restrict__ partial)
{
    const int b   = blockIdx.x / SEG;
    const int seg = blockIdx.x % SEG;
    const int t   = threadIdx.x;
    const int o0  = seg * CHUNK;
    const int n   = min(CHUNK, O_DIM - o0);   // 63, except last seg = 55

    __shared__ float ro_s[CHUNK * DS];         // 1.5 KB
    __shared__ float part_s[OSUB][M_DIM][9];   // 32.4 KB (+1 pad)
    __shared__ float wfold[10];                // wl[0..5], we, wr[0..2]

    const int mg = t % 25;   // consecutive lanes -> consecutive m (coalesced)
    const int g  = t / 25;   // o-subgroup 0..8 (t<225)

    // Issue the hot-loop loads FIRST: 14 outstanding 16B loads/thread.
    // OOB rows are clamped to n-1 (valid memory) and zeroed via predicate.
    float4 pt[TRIPS];
    int4   av[TRIPS];
    if (t < 25 * OSUB) {
        const float* ptp = proc_time + ((size_t)b * O_DIM + o0) * M_DIM + mg * 4;
        #pragma unroll
        for (int k = 0; k < TRIPS; ++k) {
            const int rc = min(g + k * OSUB, n - 1);
            pt[k] = *(const float4*)(ptp + rc * M_DIM);
        }
        const int* adp = adj + ((size_t)bidx[b] * O_DIM + o0) * M_DIM + mg * 4;
        #pragma unroll
        for (int k = 0; k < TRIPS; ++k) {
            const int rc = min(g + k * OSUB, n - 1);
            av[k] = *(const int4*)(adp + rc * M_DIM);
        }
    }

    // Stage this segment's raw_opes (n*6 <= 378 floats).
    {
        const float* rop = raw_opes + ((size_t)b * O_DIM + o0) * DS;
        const int tot = n * DS;
        if (t < tot) ro_s[t] = rop[t];
        if (t + 256 < tot) ro_s[t + 256] = rop[t + 256];
    }

    // Wave-parallel weight fold (wave 3): butterfly over 32 lanes (R8 win).
    if (t >= 192) {
        const int l = t - 192;
        const int f = l & 31;
        float al = attn_l[f], ar = attn_r[f];
        float p[10];
        #pragma unroll
        for (int d = 0; d < DS; ++d) p[d] = Wsrc[d * F_DIM + f] * al;
        p[6] = Wedge[f] * al;
        #pragma unroll
        for (int d = 0; d < DD; ++d) p[7 + d] = Wdst[d * F_DIM + f] * ar;
        #pragma unroll
        for (int s = 1; s < 32; s <<= 1) {
            #pragma unroll
            for (int k = 0; k < 10; ++k) p[k] += __shfl_xor(p[k], s);
        }
        if (l == 0) {
            #pragma unroll
            for (int k = 0; k < 10; ++k) wfold[k] = p[k];
        }
    }
    __syncthreads();

    if (t < 25 * OSUB) {
        float wl[DS], wr[DD], we;
        #pragma unroll
        for (int d = 0; d < DS; ++d) wl[d] = wfold[d];
        we = wfold[6];
        #pragma unroll
        for (int d = 0; d < DD; ++d) wr[d] = wfold[7 + d];

        const float* rm = raw_mas + ((size_t)b * M_DIM + mg * 4) * DD;
        float4 er;
        er.x = fmaf(rm[0], wr[0], fmaf(rm[1],  wr[1], rm[2]  * wr[2]));
        er.y = fmaf(rm[3], wr[0], fmaf(rm[4],  wr[1], rm[5]  * wr[2]));
        er.z = fmaf(rm[6], wr[0], fmaf(rm[7],  wr[1], rm[8]  * wr[2]));
        er.w = fmaf(rm[9], wr[0], fmaf(rm[10], wr[1], rm[11] * wr[2]));

        float4 den = make_float4(0, 0, 0, 0), spa = make_float4(0, 0, 0, 0);
        float4 sd[DS];
        #pragma unroll
        for (int d = 0; d < DS; ++d) sd[d] = make_float4(0, 0, 0, 0);

        #pragma unroll
        for (int k = 0; k < TRIPS; ++k) {
            const int row = g + k * OSUB;
            const int rc  = min(row, n - 1);
            const bool valid = row < n;
            float ro[DS];
            #pragma unroll
            for (int d = 0; d < DS; ++d) ro[d] = ro_s[rc * DS + d];
            float elr = 0.f;
            #pragma unroll
            for (int d = 0; d < DS; ++d) elr = fmaf(ro[d], wl[d], elr);

            float s0 = elr + er.x + we * pt[k].x;
            float s1 = elr + er.y + we * pt[k].y;
            float s2 = elr + er.z + we * pt[k].z;
            float s3 = elr + er.w + we * pt[k].w;
            s0 = fmaxf(s0, 0.2f * s0); s1 = fmaxf(s1, 0.2f * s1);
            s2 = fmaxf(s2, 0.2f * s2); s3 = fmaxf(s3, 0.2f * s3);
            float p0 = (valid && av[k].x == 1) ? __expf(s0) : 0.f;
            float p1 = (valid && av[k].y == 1) ? __expf(s1) : 0.f;
            float p2 = (valid && av[k].z == 1) ? __expf(s2) : 0.f;
            float p3 = (valid && av[k].w == 1) ? __expf(s3) : 0.f;
            den.x += p0; den.y += p1; den.z += p2; den.w += p3;
            spa.x = fmaf(p0, pt[k].x, spa.x); spa.y = fmaf(p1, pt[k].y, spa.y);
            spa.z = fmaf(p2, pt[k].z, spa.z); spa.w = fmaf(p3, pt[k].w, spa.w);
            #pragma unroll
            for (int d = 0; d < DS; ++d) {
                sd[d].x = fmaf(p0, ro[d], sd[d].x);
                sd[d].y = fmaf(p1, ro[d], sd[d].y);
                sd[d].z = fmaf(p2, ro[d], sd[d].z);
                sd[d].w = fmaf(p3, ro[d], sd[d].w);
            }
        }

        #pragma unroll
        for (int j = 0; j < 4; ++j) {
            const int m = mg * 4 + j;
            float* ps = part_s[g][m];
            ps[0] = j == 0 ? den.x : j == 1 ? den.y : j == 2 ? den.z : den.w;
            ps[1] = j == 0 ? spa.x : j == 1 ? spa.y : j == 2 ? spa.z : spa.w;
            #pragma unroll
            for (int d = 0; d < DS; ++d)
                ps[2 + d] = j == 0 ? sd[d].x : j == 1 ? sd[d].y : j == 2 ? sd[d].z : sd[d].w;
        }
    }
    __syncthreads();

    // Reduce over OSUB groups and write [m][8] partials.
    if (t < 2 * M_DIM) {
        const int m = t % M_DIM, half = t / M_DIM;
        float a[4] = {0, 0, 0, 0};
        #pragma unroll
        for (int gg = 0; gg < OSUB; ++gg) {
            #pragma unroll
            for (int k = 0; k < 4; ++k) a[k] += part_s[gg][m][half * 4 + k];
        }
        *(float4*)(partial + (((size_t)b * SEG + seg) * M_DIM + m) * 8 + half * 4) =
            make_float4(a[0], a[1], a[2], a[3]);
    }
}

// Kernel 2: reduce segments, normalize, emit sigmoid output. Grid = B*4.
__global__ __launch_bounds__(256) void gat_final(
    const float* __restrict__ raw_mas,    // [B,M,DD]
    const float* __restrict__ Wsrc,       // [DS,F]
    const float* __restrict__ Wdst,       // [DD,F]
    const float* __restrict__ Wedge,      // [F]
    const float* __restrict__ attn_r,     // [F]
    const float* __restrict__ partial,
    float* __restrict__ out)              // [B,M,F]
{
    const int b  = blockIdx.x >> 2;
    const int m0 = (blockIdx.x & 3) * MT;
    const int t  = threadIdx.x;

    __shared__ float smd[MT][9];
    __shared__ float wr_s[DD];

    // Wave-parallel attn_r fold (wave 3, overlaps the reduce phase).
    if (t >= 192) {
        const int f = t & 31;
        float ar = attn_r[f];
        float p[DD];
        #pragma unroll
        for (int d = 0; d < DD; ++d) p[d] = Wdst[d * F_DIM + f] * ar;
        #pragma unroll
        for (int s = 1; s < 32; s <<= 1) {
            #pragma unroll
            for (int d = 0; d < DD; ++d) p[d] += __shfl_xor(p[d], s);
        }
        if ((t & 63) == 0) {
            #pragma unroll
            for (int d = 0; d < DD; ++d) wr_s[d] = p[d];
        }
    }

    if (t < MT * 8) {
        const int ml = t % MT;
        const int k  = t / MT;
        const float* p = partial + (((size_t)b * SEG) * M_DIM + m0 + ml) * 8 + k;
        float acc = 0.f;
        #pragma unroll
        for (int s = 0; s < SEG; ++s) acc += p[(size_t)s * M_DIM * 8];
        smd[ml][k] = acc;
    }
    __syncthreads();

    if (t < MT) {
        const float* rm = raw_mas + ((size_t)b * M_DIM + m0 + t) * DD;
        float er = fmaf(rm[0], wr_s[0], fmaf(rm[1], wr_s[1], rm[2] * wr_s[2]));
        float skk = 2.f * er;
        skk = fmaxf(skk, 0.2f * skk);
        float pkk = __expf(skk);
        float den = smd[t][0], spa = smd[t][1];
        float s0 = smd[t][2], s1 = smd[t][3], s2 = smd[t][4],
              s3 = smd[t][5], s4 = smd[t][6], s5 = smd[t][7];
        float inv = 1.f / (den + pkk);
        smd[t][0] = s0 * inv; smd[t][1] = s1 * inv; smd[t][2] = s2 * inv;
        smd[t][3] = s3 * inv; smd[t][4] = s4 * inv; smd[t][5] = s5 * inv;
        smd[t][6] = spa * inv;
        smd[t][7] = pkk * inv;
    }
    __syncthreads();

    for (int idx = t; idx < MT * F_DIM; idx += 256) {
        const int ml = idx >> 5;
        const int f  = idx & 31;
        float v = smd[ml][6] * Wedge[f];
        #pragma unroll
        for (int d = 0; d < DS; ++d) v = fmaf(smd[ml][d], Wsrc[d * F_DIM + f], v);
        const float* rm = raw_mas + ((size_t)b * M_DIM + m0 + ml) * DD;
        float fd = 0.f;
        #pragma unroll
        for (int d = 0; d < DD; ++d) fd = fmaf(rm[d], Wdst[d * F_DIM + f], fd);
        v = fmaf(fd, smd[ml][7], v);
        out[((size_t)b * M_DIM + m0 + ml) * F_DIM + f] = 1.f / (1.f + __expf(-v));
    }
}

extern "C" void kernel_launch(void* const* d_in, const int* in_sizes, int n_in,
                              void* d_out, int out_size, void* d_ws, size_t ws_size,
                              hipStream_t stream) {
    const float* raw_opes  = (const float*)d_in[0];
    const float* raw_mas   = (const float*)d_in[1];
    const float* proc_time = (const float*)d_in[2];
    const int*   adj       = (const int*)d_in[3];
    const int*   bidx      = (const int*)d_in[4];
    const float* Wsrc      = (const float*)d_in[5];
    const float* Wdst      = (const float*)d_in[6];
    const float* Wedge     = (const float*)d_in[7];
    const float* attn_l    = (const float*)d_in[8];
    const float* attn_r    = (const float*)d_in[9];
    float* out     = (float*)d_out;
    float* partial = (float*)d_ws;   // [B,SEG,M,8] = 1.64 MB

    gat_partial<<<B_DIM * SEG, 256, 0, stream>>>(raw_opes, raw_mas, proc_time, adj, bidx,
                                                 Wsrc, Wdst, Wedge, attn_l, attn_r, partial);
    gat_final<<<B_DIM * 4, 256, 0, stream>>>(raw_mas, Wsrc, Wdst, Wedge, attn_r, partial, out);
}